// Round 13
// baseline (131.611 us; speedup 1.0000x reference)
//
#include <hip/hip_runtime.h>

// HistoLoss: B=1024, T=256, C=16, NB=64; TC=4096; x flat = [b][tc]
//
// R12 (best, 89.96us): integer range-check inner loop, k1+k2. Budget model:
// fill 43.5 + restores ~3.5 + gaps ~6 + k1 (~25: staging/ramp 10 + compute
// ~15 @ ~3.2cyc/inst vcc spacing) + k2 ~3 + gap ~2. Round-13 removes the
// k2 dispatch + its node gap (~5us) by fusing the loss epilogue into k1:
// last-arriver-per-t pattern (8 chunk-blocks/t bump an agent-scope counter;
// the 8th computes t's 1024 loss items = exactly k2's per-t work).
//  * no spinning -> no deadlock regardless of dispatch order/residency.
//  * poison-safe: ctr[] and out live in poisoned (0xAA) memory -> every
//    participant CASes 0xAAAAAAAA->0 before its add; atomics on one address
//    are totally ordered, so the first op is always a clearing CAS. Loss
//    partials are >=0 floats (sign bit 0) so no legit value aliases poison;
//    correctness run memsets out to 0 -> CAS fails harmlessly.
//  * visibility: __syncthreads() drains vmcnt(0) (all count-stores reach
//    L2), then tid0's ACQ_REL agent fetch_add = release(L2 wb) + acquire
//    (L2 inv) -> the 8th block's cross-XCD count reads are fresh.
// Inner loop/staging byte-identical to R12 (clean attribution).

#define T_DIM   256
#define C_DIM   16
#define NB      64
#define TC      4096
#define CHUNKS  16
#define BBLK    128
#define KPT     8
#define PITCHI  132            // xsi row pitch in i32 (128 + 4 pad)
#define QSCALE  4096.0f        // fixed-point scale (x ~ [-4,4] -> |xi|<2^15)
#define POISON  0xAAAAAAAAu

__global__ __launch_bounds__(256, 8) void histo_fused_kernel(
    const float* __restrict__ x,       // [1024, 4096]
    const float* __restrict__ locs,    // [4096, 64]
    const float* __restrict__ deltas,  // [4096]
    const float* __restrict__ dens,    // [4096, 64]
    unsigned char* __restrict__ counts,// [CHUNKS][4096][64] u8 (ws)
    unsigned* __restrict__ ctr,        // [256] arrival counters (ws)
    float* __restrict__ out)           // [1]
{
    __shared__ int xsi[C_DIM * PITCHI];          // 16 x 132 i32 = 8448 B
    __shared__ int slast;
    const int tid   = threadIdx.x;
    const int t     = blockIdx.x & 255;
    const int chunk = blockIdx.x >> 8;           // 0..7 (128 b each)

    // ---- stage x[chunk*128 .. +127][t*16 .. +15] -> i32 fixed-point ----
    {
        const int bpair = tid >> 2;              // 0..63
        const int c4    = (tid & 3) * 4;
        const int b0    = 2 * bpair;
        const float* r0 = x + (size_t)(chunk * BBLK + b0) * TC + t * C_DIM + c4;
        const float4 va = *(const float4*)r0;
        const float4 vb = *(const float4*)(r0 + TC);
        const float a[4] = {va.x, va.y, va.z, va.w};
        const float b[4] = {vb.x, vb.y, vb.z, vb.w};
#pragma unroll
        for (int k = 0; k < 4; ++k) {
            xsi[(c4 + k) * PITCHI + b0]     = (int)__float2int_rn(a[k] * QSCALE);
            xsi[(c4 + k) * PITCHI + b0 + 1] = (int)__float2int_rn(b[k] * QSCALE);
        }
    }

    const int bg = tid >> 7;           // b-subgroup: 64 b's each
    const int r  = tid & 127;
    const int c  = r >> 3;             // 0..15
    const int kq = r & 7;              // bins [kq*8, kq*8+8)
    const int tc = t * C_DIM + c;

    const float hf = 0.5f * deltas[tc];
    const int   qw = __float2int_rn(2.0f * hf * QSCALE);   // window width

    int qlo[KPT];
    const float* lp = locs + (size_t)tc * NB + kq * KPT;
#pragma unroll
    for (int j = 0; j < KPT; ++j)
        qlo[j] = __float2int_rn((lp[j] - hf) * QSCALE);    // window low edge

    int acc[KPT];
#pragma unroll
    for (int j = 0; j < KPT; ++j) acc[j] = 0;

    __syncthreads();

    // ---- count: 16 x (ds_read_b128 + 8 bins x 4 x 3 VOP2) — R12 inner ----
    const int4* xr = (const int4*)(xsi + c * PITCHI + bg * 64);
#pragma unroll 4
    for (int g = 0; g < 16; ++g) {
        const int4 u = xr[g];
        const int xi[4] = {u.x, u.y, u.z, u.w};
#pragma unroll
        for (int j = 0; j < KPT; ++j) {
#pragma unroll
            for (int q = 0; q < 4; ++q) {
                int tmp;
                asm("v_sub_u32 %0, %2, %3\n\t"
                    "v_cmp_lt_u32 vcc, %0, %4\n\t"
                    "v_addc_co_u32 %1, vcc, 0, %1, vcc"
                    : "=&v"(tmp), "+v"(acc[j])
                    : "v"(xi[q]), "v"(qlo[j]), "v"(qw)
                    : "vcc");
            }
        }
    }

    unsigned long long pack = 0;
#pragma unroll
    for (int j = 0; j < KPT; ++j)
        pack |= (unsigned long long)(unsigned)acc[j] << (8 * j);  // <=64 each
    *(unsigned long long*)(counts + (size_t)(chunk * 2 + bg) * (TC * NB)
                                  + (size_t)tc * NB + kq * KPT) = pack;

    // ---- arrival: 8 blocks per t; the 8th runs the epilogue for t ----
    __syncthreads();   // drains vmcnt(0): all this block's count-stores in L2
    if (tid == 0) {
        unsigned expected = POISON;   // clear harness poison exactly once
        __hip_atomic_compare_exchange_strong(&ctr[t], &expected, 0u,
            __ATOMIC_RELAXED, __ATOMIC_RELAXED, __HIP_MEMORY_SCOPE_AGENT);
        const unsigned old = __hip_atomic_fetch_add(&ctr[t], 1u,
            __ATOMIC_ACQ_REL, __HIP_MEMORY_SCOPE_AGENT);
        slast = (old == 7u);
    }
    __syncthreads();
    if (!slast) return;

    // ---- epilogue (k2's per-t work): 1024 items = 256 thr x 4 ----
    const int i0 = t * (C_DIM * NB) + tid * 4;   // 4 consecutive items, same tc
    int cnt[4] = {0, 0, 0, 0};
#pragma unroll
    for (int ch = 0; ch < CHUNKS; ++ch) {
        const unsigned u = *(const unsigned*)(counts + (size_t)ch * (TC * NB) + i0);
#pragma unroll
        for (int q = 0; q < 4; ++q)
            cnt[q] += (int)((u >> (8 * q)) & 0xffu);
    }

    const float delta = deltas[i0 >> 6];
    const float4 dv = *(const float4*)(dens + i0);
    // Reference order: (cnt/1024) exact, then / delta.
    float s = fabsf((cnt[0] * (1.0f / 1024.0f)) / delta - dv.x)
            + fabsf((cnt[1] * (1.0f / 1024.0f)) / delta - dv.y)
            + fabsf((cnt[2] * (1.0f / 1024.0f)) / delta - dv.z)
            + fabsf((cnt[3] * (1.0f / 1024.0f)) / delta - dv.w);

#pragma unroll
    for (int off = 32; off > 0; off >>= 1)
        s += __shfl_down(s, off, 64);

    __shared__ float sb[4];
    if ((tid & 63) == 0) sb[tid >> 6] = s;
    __syncthreads();

    if (tid == 0) {
        unsigned expected = POISON;   // unpoison out exactly once (see header)
        __hip_atomic_compare_exchange_strong((unsigned*)out, &expected, 0u,
            __ATOMIC_RELAXED, __ATOMIC_RELAXED, __HIP_MEMORY_SCOPE_AGENT);
        // REG * mean over (t,c,k) = sum / 262144
        atomicAdd(out, (sb[0] + sb[1] + sb[2] + sb[3]) * (1.0f / 262144.0f));
    }
}

extern "C" void kernel_launch(void* const* d_in, const int* in_sizes, int n_in,
                              void* d_out, int out_size, void* d_ws, size_t ws_size,
                              hipStream_t stream) {
    const float* x      = (const float*)d_in[0];  // x_fake    [1024,256,16]
    const float* locs   = (const float*)d_in[1];  // locs      [256,16,64]
    const float* deltas = (const float*)d_in[2];  // deltas    [256,16]
    const float* dens   = (const float*)d_in[3];  // densities [256,16,64]
    float* out = (float*)d_out;

    unsigned char* cnts = (unsigned char*)d_ws;                       // 4 MB
    unsigned* ctr = (unsigned*)((char*)d_ws + (size_t)CHUNKS * TC * NB); // 1 KB

    histo_fused_kernel<<<T_DIM * 8, 256, 0, stream>>>(
        x, locs, deltas, dens, cnts, ctr, out);
}

// Round 14
// 93.134 us; speedup vs baseline: 1.4131x; 1.4131x over previous
//
#include <hip/hip_runtime.h>

// HistoLoss: B=1024, T=256, C=16, NB=64; TC=4096; x flat = [b][tc]
//
// R13 post-mortem: per-block agent-scope ACQ_REL fences cost ~45us (L2
// invalidates, VALUBusy 80->28%) to save a ~5us dispatch -> reverted.
// R14 = R12 (best, 89.96us) with ONE change: the inner asm uses dual
// chains with PRIVATE sgpr carry pairs instead of shared vcc.
//   R12 residual: compute ~3.2 cyc/inst vs 2.0 ideal; candidate mechanism
//   is the v_cmp->v_addc RAW through the single vcc (64-bit sgpr write,
//   structurally shared by all 8 j-chains). Here: 12-inst block per
//   (j, 4 indicators), two independent chains (accA/accB, cA/cB sgpr
//   pairs), cmp->addc spacing 2. Inst/indicator unchanged (3.0).
// Everything else byte-identical to R12: integer range-check counting
// (fixed-point x4096, fuzz 1.2e-4 << validated fp16 fuzz; absmax 0 in
// R12), line-exact staging, u8-packed per-chunk counts, k2 + atomicAdd.
// Harness fixed cost ~60us (43.5us 256MB ws re-poison + restores + gaps).

#define T_DIM   256
#define C_DIM   16
#define NB      64
#define TC      4096
#define CHUNKS  16
#define BBLK    128
#define KPT     8
#define PITCHI  132            // xsi row pitch in i32 (128 + 4 pad)
#define QSCALE  4096.0f        // fixed-point scale (x ~ [-4,4] -> |xi|<2^15)

__global__ __launch_bounds__(256, 8) void histo_count_kernel(
    const float* __restrict__ x,       // [1024, 4096]
    const float* __restrict__ locs,    // [4096, 64]
    const float* __restrict__ deltas,  // [4096]
    unsigned char* __restrict__ counts,// [CHUNKS][4096][64] u8
    float* __restrict__ out)           // [1] (zeroed for k2's atomics)
{
    __shared__ int xsi[C_DIM * PITCHI];          // 16 x 132 i32 = 8448 B
    const int tid   = threadIdx.x;
    const int t     = blockIdx.x & 255;
    const int chunk = blockIdx.x >> 8;           // 0..7 (128 b each)

    if (blockIdx.x == 0 && tid == 0) out[0] = 0.0f;

    // Stage x[chunk*128 .. +127][t*16 .. +15] -> i32 fixed-point (x*4096).
    {
        const int bpair = tid >> 2;              // 0..63
        const int c4    = (tid & 3) * 4;
        const int b0    = 2 * bpair;
        const float* r0 = x + (size_t)(chunk * BBLK + b0) * TC + t * C_DIM + c4;
        const float4 va = *(const float4*)r0;
        const float4 vb = *(const float4*)(r0 + TC);
        const float a[4] = {va.x, va.y, va.z, va.w};
        const float b[4] = {vb.x, vb.y, vb.z, vb.w};
#pragma unroll
        for (int k = 0; k < 4; ++k) {
            xsi[(c4 + k) * PITCHI + b0]     = (int)__float2int_rn(a[k] * QSCALE);
            xsi[(c4 + k) * PITCHI + b0 + 1] = (int)__float2int_rn(b[k] * QSCALE);
        }
    }

    const int bg = tid >> 7;           // b-subgroup: 64 b's each
    const int r  = tid & 127;
    const int c  = r >> 3;             // 0..15
    const int kq = r & 7;              // bins [kq*8, kq*8+8)
    const int tc = t * C_DIM + c;

    const float hf = 0.5f * deltas[tc];
    const int   qw = __float2int_rn(2.0f * hf * QSCALE);   // window width

    int qlo[KPT];
    const float* lp = locs + (size_t)tc * NB + kq * KPT;
#pragma unroll
    for (int j = 0; j < KPT; ++j)
        qlo[j] = __float2int_rn((lp[j] - hf) * QSCALE);    // window low edge

    int accA[KPT], accB[KPT];
#pragma unroll
    for (int j = 0; j < KPT; ++j) { accA[j] = 0; accB[j] = 0; }

    __syncthreads();

    // 16 iters x (1 ds_read_b128 = 4 xi) x 8 bins x 12-inst dual-chain asm.
    // Chains A (xi0,xi2) and B (xi1,xi3) have private sgpr carry pairs ->
    // no shared-vcc structural hazard; cmp->addc spacing 2.
    const int4* xr = (const int4*)(xsi + c * PITCHI + bg * 64);
#pragma unroll 4
    for (int g = 0; g < 16; ++g) {
        const int4 u = xr[g];
#pragma unroll
        for (int j = 0; j < KPT; ++j) {
            int tA, tB;
            unsigned long long cA, cB;   // private sgpr pairs
            asm("v_sub_u32 %0, %6, %10\n\t"
                "v_sub_u32 %1, %7, %10\n\t"
                "v_cmp_lt_u32 %2, %0, %11\n\t"
                "v_cmp_lt_u32 %3, %1, %11\n\t"
                "v_addc_co_u32 %4, %2, 0, %4, %2\n\t"
                "v_addc_co_u32 %5, %3, 0, %5, %3\n\t"
                "v_sub_u32 %0, %8, %10\n\t"
                "v_sub_u32 %1, %9, %10\n\t"
                "v_cmp_lt_u32 %2, %0, %11\n\t"
                "v_cmp_lt_u32 %3, %1, %11\n\t"
                "v_addc_co_u32 %4, %2, 0, %4, %2\n\t"
                "v_addc_co_u32 %5, %3, 0, %5, %3"
                : "=&v"(tA), "=&v"(tB), "=&s"(cA), "=&s"(cB),
                  "+v"(accA[j]), "+v"(accB[j])
                : "v"(u.x), "v"(u.y), "v"(u.z), "v"(u.w),
                  "v"(qlo[j]), "v"(qw));
        }
    }

    unsigned long long pack = 0;
#pragma unroll
    for (int j = 0; j < KPT; ++j) {
        const unsigned cj = (unsigned)(accA[j] + accB[j]);   // <=64 exact
        pack |= (unsigned long long)cj << (8 * j);
    }
    *(unsigned long long*)(counts + (size_t)(chunk * 2 + bg) * (TC * NB)
                                  + (size_t)tc * NB + kq * KPT) = pack;
}

__global__ __launch_bounds__(256) void histo_loss_kernel(
    const unsigned char* __restrict__ counts, // [CHUNKS][4096][64]
    const float* __restrict__ deltas,         // [4096]
    const float* __restrict__ dens,           // [4096, 64]
    float* __restrict__ out)                  // [1]
{
    const int gid = blockIdx.x * 256 + threadIdx.x;
    const int i0  = gid * 4;                  // 4 consecutive items, same tc

    int cnt[4] = {0, 0, 0, 0};
#pragma unroll
    for (int ch = 0; ch < CHUNKS; ++ch) {
        const unsigned u = *(const unsigned*)(counts + (size_t)ch * (TC * NB) + i0);
#pragma unroll
        for (int q = 0; q < 4; ++q)
            cnt[q] += (int)((u >> (8 * q)) & 0xffu);
    }

    const float delta = deltas[i0 >> 6];
    const float4 dv = *(const float4*)(dens + i0);
    // Reference order: (cnt/1024) exact, then / delta.
    float s = fabsf((cnt[0] * (1.0f / 1024.0f)) / delta - dv.x)
            + fabsf((cnt[1] * (1.0f / 1024.0f)) / delta - dv.y)
            + fabsf((cnt[2] * (1.0f / 1024.0f)) / delta - dv.z)
            + fabsf((cnt[3] * (1.0f / 1024.0f)) / delta - dv.w);

#pragma unroll
    for (int off = 32; off > 0; off >>= 1)
        s += __shfl_down(s, off, 64);

    __shared__ float sb[4];
    if ((threadIdx.x & 63) == 0) sb[threadIdx.x >> 6] = s;
    __syncthreads();

    if (threadIdx.x == 0)   // REG * mean over (t,c,k) = sum / 262144
        atomicAdd(out, (sb[0] + sb[1] + sb[2] + sb[3]) * (1.0f / 262144.0f));
}

extern "C" void kernel_launch(void* const* d_in, const int* in_sizes, int n_in,
                              void* d_out, int out_size, void* d_ws, size_t ws_size,
                              hipStream_t stream) {
    const float* x      = (const float*)d_in[0];  // x_fake    [1024,256,16]
    const float* locs   = (const float*)d_in[1];  // locs      [256,16,64]
    const float* deltas = (const float*)d_in[2];  // deltas    [256,16]
    const float* dens   = (const float*)d_in[3];  // densities [256,16,64]
    float* out = (float*)d_out;
    unsigned char* cnts = (unsigned char*)d_ws;   // 4 MB scratch

    histo_count_kernel<<<T_DIM * 8, 256, 0, stream>>>(x, locs, deltas, cnts, out);
    histo_loss_kernel<<<(TC * NB) / (256 * 4), 256, 0, stream>>>(cnts, deltas, dens, out);
}

// Round 15
// 89.533 us; speedup vs baseline: 1.4700x; 1.0402x over previous
//
#include <hip/hip_runtime.h>

// HistoLoss: B=1024, T=256, C=16, NB=64; TC=4096; x flat = [b][tc]
//
// FINAL (= R12, best verified 89.96us, absmax 0.0). Session ceiling:
//   43.5us harness ws re-poison (256MB, BW-bound) + ~9us restores/gaps
// + ~25us count kernel (integer range-check, ~3cyc/inst issue ceiling at
//   16 waves/CU — fp16-pk/ILP/sgpr-carry/persistence all neutral-or-worse)
// + ~4us reduce. Fusion via device-scope atomics regresses (R13: +45us).
//
// k1: 256 thr = 2 b-subgroups x (16 c x 8 kq); block = (t, 128-b chunk);
//     grid 2048. x staged as i32 fixed-point (x*4096; fuzz 1.2e-4 <<
//     7.7e-3 threshold, absmax 0 observed), rows xsi[c][132] (disjoint
//     4-bank spans/wave, 8-way broadcast: conflict-free ds_read_b128).
//     Inner: 3 VOP2/indicator via shared-vcc asm (fastest encoding, R14
//     falsified the private-sgpr variant). Line-exact staging (~17MB fetch).
//     Counts <=64 -> 8 x u8 pack -> one 8B store.
// k2: sum 16 chunk u8s, loss, block-reduce, one atomicAdd/block (out[0]
//     zeroed by k1 block 0; stream-ordered).

#define T_DIM   256
#define C_DIM   16
#define NB      64
#define TC      4096
#define CHUNKS  16
#define BBLK    128
#define KPT     8
#define PITCHI  132            // xsi row pitch in i32 (128 + 4 pad)
#define QSCALE  4096.0f        // fixed-point scale (x ~ [-4,4] -> |xi|<2^15)

__global__ __launch_bounds__(256, 8) void histo_count_kernel(
    const float* __restrict__ x,       // [1024, 4096]
    const float* __restrict__ locs,    // [4096, 64]
    const float* __restrict__ deltas,  // [4096]
    unsigned char* __restrict__ counts,// [CHUNKS][4096][64] u8
    float* __restrict__ out)           // [1] (zeroed for k2's atomics)
{
    __shared__ int xsi[C_DIM * PITCHI];          // 16 x 132 i32 = 8448 B
    const int tid   = threadIdx.x;
    const int t     = blockIdx.x & 255;
    const int chunk = blockIdx.x >> 8;           // 0..7 (128 b each)

    if (blockIdx.x == 0 && tid == 0) out[0] = 0.0f;

    // Stage x[chunk*128 .. +127][t*16 .. +15] -> i32 fixed-point (x*4096).
    {
        const int bpair = tid >> 2;              // 0..63
        const int c4    = (tid & 3) * 4;
        const int b0    = 2 * bpair;
        const float* r0 = x + (size_t)(chunk * BBLK + b0) * TC + t * C_DIM + c4;
        const float4 va = *(const float4*)r0;
        const float4 vb = *(const float4*)(r0 + TC);
        const float a[4] = {va.x, va.y, va.z, va.w};
        const float b[4] = {vb.x, vb.y, vb.z, vb.w};
#pragma unroll
        for (int k = 0; k < 4; ++k) {
            xsi[(c4 + k) * PITCHI + b0]     = (int)__float2int_rn(a[k] * QSCALE);
            xsi[(c4 + k) * PITCHI + b0 + 1] = (int)__float2int_rn(b[k] * QSCALE);
        }
    }

    const int bg = tid >> 7;           // b-subgroup: 64 b's each
    const int r  = tid & 127;
    const int c  = r >> 3;             // 0..15
    const int kq = r & 7;              // bins [kq*8, kq*8+8)
    const int tc = t * C_DIM + c;

    const float hf = 0.5f * deltas[tc];
    const int   qw = __float2int_rn(2.0f * hf * QSCALE);   // window width

    int qlo[KPT];
    const float* lp = locs + (size_t)tc * NB + kq * KPT;
#pragma unroll
    for (int j = 0; j < KPT; ++j)
        qlo[j] = __float2int_rn((lp[j] - hf) * QSCALE);    // window low edge

    int acc[KPT];
#pragma unroll
    for (int j = 0; j < KPT; ++j) acc[j] = 0;

    __syncthreads();

    // 16 iters x (1 ds_read_b128 = 4 xi) x 8 bins x 4 x 3 VOP2 inst.
    const int4* xr = (const int4*)(xsi + c * PITCHI + bg * 64);
#pragma unroll 4
    for (int g = 0; g < 16; ++g) {
        const int4 u = xr[g];
        const int xi[4] = {u.x, u.y, u.z, u.w};
#pragma unroll
        for (int j = 0; j < KPT; ++j) {
#pragma unroll
            for (int q = 0; q < 4; ++q) {
                int tmp;
                asm("v_sub_u32 %0, %2, %3\n\t"
                    "v_cmp_lt_u32 vcc, %0, %4\n\t"
                    "v_addc_co_u32 %1, vcc, 0, %1, vcc"
                    : "=&v"(tmp), "+v"(acc[j])
                    : "v"(xi[q]), "v"(qlo[j]), "v"(qw)
                    : "vcc");
            }
        }
    }

    unsigned long long pack = 0;
#pragma unroll
    for (int j = 0; j < KPT; ++j)
        pack |= (unsigned long long)(unsigned)acc[j] << (8 * j);  // <=64 each
    *(unsigned long long*)(counts + (size_t)(chunk * 2 + bg) * (TC * NB)
                                  + (size_t)tc * NB + kq * KPT) = pack;
}

__global__ __launch_bounds__(256) void histo_loss_kernel(
    const unsigned char* __restrict__ counts, // [CHUNKS][4096][64]
    const float* __restrict__ deltas,         // [4096]
    const float* __restrict__ dens,           // [4096, 64]
    float* __restrict__ out)                  // [1]
{
    const int gid = blockIdx.x * 256 + threadIdx.x;
    const int i0  = gid * 4;                  // 4 consecutive items, same tc

    int cnt[4] = {0, 0, 0, 0};
#pragma unroll
    for (int ch = 0; ch < CHUNKS; ++ch) {
        const unsigned u = *(const unsigned*)(counts + (size_t)ch * (TC * NB) + i0);
#pragma unroll
        for (int q = 0; q < 4; ++q)
            cnt[q] += (int)((u >> (8 * q)) & 0xffu);
    }

    const float delta = deltas[i0 >> 6];
    const float4 dv = *(const float4*)(dens + i0);
    // Reference order: (cnt/1024) exact, then / delta.
    float s = fabsf((cnt[0] * (1.0f / 1024.0f)) / delta - dv.x)
            + fabsf((cnt[1] * (1.0f / 1024.0f)) / delta - dv.y)
            + fabsf((cnt[2] * (1.0f / 1024.0f)) / delta - dv.z)
            + fabsf((cnt[3] * (1.0f / 1024.0f)) / delta - dv.w);

#pragma unroll
    for (int off = 32; off > 0; off >>= 1)
        s += __shfl_down(s, off, 64);

    __shared__ float sb[4];
    if ((threadIdx.x & 63) == 0) sb[threadIdx.x >> 6] = s;
    __syncthreads();

    if (threadIdx.x == 0)   // REG * mean over (t,c,k) = sum / 262144
        atomicAdd(out, (sb[0] + sb[1] + sb[2] + sb[3]) * (1.0f / 262144.0f));
}

extern "C" void kernel_launch(void* const* d_in, const int* in_sizes, int n_in,
                              void* d_out, int out_size, void* d_ws, size_t ws_size,
                              hipStream_t stream) {
    const float* x      = (const float*)d_in[0];  // x_fake    [1024,256,16]
    const float* locs   = (const float*)d_in[1];  // locs      [256,16,64]
    const float* deltas = (const float*)d_in[2];  // deltas    [256,16]
    const float* dens   = (const float*)d_in[3];  // densities [256,16,64]
    float* out = (float*)d_out;
    unsigned char* cnts = (unsigned char*)d_ws;   // 4 MB scratch

    histo_count_kernel<<<T_DIM * 8, 256, 0, stream>>>(x, locs, deltas, cnts, out);
    histo_loss_kernel<<<(TC * NB) / (256 * 4), 256, 0, stream>>>(cnts, deltas, dens, out);
}